// Round 9
// baseline (527.314 us; speedup 1.0000x reference)
//
#include <hip/hip_runtime.h>
#include <hip/hip_bf16.h>

// MHSA: B=4, P=4096, C=256, H=4, D=64. fp32 in/out, bf16 MFMA internally.
#define DIMC 256
#define NHEADS 4
#define HDIM 64
#define BATCH 4
#define SEQ 4096
#define MTOT (BATCH*SEQ)   // 16384
#define SCALE_LOG2E 0.18033688011112042f  // 0.125 * log2(e); softmax done in exp2 domain

typedef __attribute__((ext_vector_type(8))) __bf16 bf16x8;
typedef __attribute__((ext_vector_type(4))) __bf16 bf16x4;
typedef __attribute__((ext_vector_type(2))) __bf16 bf16x2;
typedef __attribute__((ext_vector_type(4))) float f32x4;
typedef __attribute__((ext_vector_type(2))) unsigned uint2v;
typedef __attribute__((ext_vector_type(4))) unsigned uint4v;

__device__ inline void gll16(const void* g, void* l) {
  // async global->LDS, 16B per lane. LDS dest must be wave-uniform base + lane*16.
  __builtin_amdgcn_global_load_lds((const __attribute__((address_space(1))) unsigned int*)g,
                                   (__attribute__((address_space(3))) unsigned int*)l, 16, 0, 0);
}

// Single v_exp_f32 via the compiler intrinsic. NOTE (R5 post-mortem): raw
// inline-asm v_exp_f32 FAILED — TRANS ops need a wait state before dependent
// VALU consumers and the compiler can't see inside asm. The builtin emits the
// same single instruction WITH correct hazard handling. Args in ~[-2,2].
__device__ inline float vexp2(float x) { return __builtin_amdgcn_exp2f(x); }

// Pack two f32 -> one u32 of 2 bf16 (RNE). Plain casts (NOT inline asm):
// compiler emits cvt_pk/cvt+pack itself and keeps hazard handling (m240).
__device__ inline unsigned pack2(float lo, float hi) {
  bf16x2 p; p[0] = (__bf16)lo; p[1] = (__bf16)hi;
  return __builtin_bit_cast(unsigned, p);
}

// Swizzled read of a 16B chunk from a row-major LDS tile with 64-bf16 (128B) rows.
// Data staged with matching pre-swizzled global source: chunk (r,c) holds global
// column (c ^ (r&7)). Kills the 128B-stride bank conflict (T2; verified R1: 6.5e7 -> 0).
__device__ inline bf16x8 swzread(const __bf16* base, int row, int c16) {
  return *reinterpret_cast<const bf16x8*>(
      reinterpret_cast<const char*>(base) + row * 128 + ((c16 ^ (row & 7)) << 4));
}

// ---------------- prep kernels ----------------

__global__ __launch_bounds__(256) void cvt_x_kernel(const float* __restrict__ x, __bf16* __restrict__ xb) {
  int i = (blockIdx.x * 256 + threadIdx.x) * 4;
  float4 v = *reinterpret_cast<const float4*>(x + i);
  bf16x4 o;
  o[0] = (__bf16)v.x; o[1] = (__bf16)v.y; o[2] = (__bf16)v.z; o[3] = (__bf16)v.w;
  *reinterpret_cast<bf16x4*>(xb + i) = o;
}

// Builds Wqkv^T [768][256] (Wq scaled by 0.125*log2e) and Wo^T [256][256].
__global__ __launch_bounds__(256) void prep_w(const float* __restrict__ Wq, const float* __restrict__ Wk,
                                              const float* __restrict__ Wv, const float* __restrict__ Wo,
                                              __bf16* __restrict__ wqkvt, __bf16* __restrict__ wot) {
  int row = blockIdx.x;        // 0..1023
  int k = threadIdx.x;         // 0..255
  if (row < 768) {
    const float* src; float scale = 1.f; int n = row & 255;
    if (row < 256)      { src = Wq; scale = SCALE_LOG2E; }
    else if (row < 512) { src = Wk; }
    else                { src = Wv; }
    wqkvt[row * 256 + k] = (__bf16)(src[k * 256 + n] * scale);
  } else {
    int n = row - 768;
    wot[n * 256 + k] = (__bf16)(Wo[k * 256 + n]);
  }
}

__global__ __launch_bounds__(256) void prep_bias(const float* __restrict__ bq, const float* __restrict__ bk,
                                                 const float* __restrict__ bv, float* __restrict__ biasq) {
  int i = blockIdx.x * 256 + threadIdx.x;  // 0..767
  biasq[i] = (i < 256) ? bq[i] * SCALE_LOG2E : (i < 512 ? bk[i - 256] : bv[i - 512]);
}

// ---------------- GEMM: C[m][n] = sum_k A[m][k]*Bt[n][k] + bias[n] ----------------
// 128x128 tile, BK=64, 4 waves (2x2 of 64x64), mfma 16x16x32 bf16. T2-swizzled LDS.
// MODE 0: scatter into q/k/v [b][h][p][d] (bf16).  MODE 1: fp32 out [m][256].
template<int MODE>
__global__ __launch_bounds__(256) void gemm_bt(const __bf16* __restrict__ A, const __bf16* __restrict__ Bt,
                                               const float* __restrict__ bias,
                                               __bf16* __restrict__ q_ws, __bf16* __restrict__ k_ws,
                                               __bf16* __restrict__ v_ws, float* __restrict__ fout) {
  __shared__ __align__(16) __bf16 As[128 * 64];
  __shared__ __align__(16) __bf16 Bs[128 * 64];
  const int tid = threadIdx.x;
  const int lane = tid & 63, wave = tid >> 6;
  const int wr = wave >> 1, wc = wave & 1;
  const int r16 = lane & 15, g4 = lane >> 4;
  const int m0 = blockIdx.y * 128, n0 = blockIdx.x * 128;
  f32x4 acc[4][4] = {};
  for (int k0 = 0; k0 < DIMC; k0 += 64) {
    #pragma unroll
    for (int it = 0; it < 4; ++it) {
      int e = it * 256 + tid;           // 16B chunk id
      int r = e >> 3, c = e & 7;
      int cs = c ^ (r & 7);             // pre-swizzled source column (rule #21)
      gll16(A  + (size_t)(m0 + r) * DIMC + k0 + cs * 8, As + e * 8);
      gll16(Bt + (size_t)(n0 + r) * DIMC + k0 + cs * 8, Bs + e * 8);
    }
    __syncthreads();
    #pragma unroll
    for (int kk = 0; kk < 2; ++kk) {
      bf16x8 af[4], bfr[4];
      #pragma unroll
      for (int mi = 0; mi < 4; ++mi)
        af[mi] = swzread(As, wr * 64 + mi * 16 + r16, kk * 4 + g4);
      #pragma unroll
      for (int ni = 0; ni < 4; ++ni)
        bfr[ni] = swzread(Bs, wc * 64 + ni * 16 + r16, kk * 4 + g4);
      #pragma unroll
      for (int mi = 0; mi < 4; ++mi)
        #pragma unroll
        for (int ni = 0; ni < 4; ++ni)
          acc[mi][ni] = __builtin_amdgcn_mfma_f32_16x16x32_bf16(af[mi], bfr[ni], acc[mi][ni], 0, 0, 0);
    }
    __syncthreads();
  }
  // Epilogue. C/D layout: col = lane&15, row = (lane>>4)*4 + reg.
  #pragma unroll
  for (int mi = 0; mi < 4; ++mi)
    #pragma unroll
    for (int ni = 0; ni < 4; ++ni)
      #pragma unroll
      for (int r = 0; r < 4; ++r) {
        int m = m0 + wr * 64 + mi * 16 + g4 * 4 + r;
        int n = n0 + wc * 64 + ni * 16 + r16;
        float v = acc[mi][ni][r] + bias[n];
        if (MODE == 0) {
          int b = m >> 12, p = m & 4095;
          int sect = n >> 8, nc = n & 255;
          int h = nc >> 6, d = nc & 63;
          __bf16 hv = (__bf16)v;
          size_t off = ((size_t)(b * NHEADS + h) * SEQ + p) * HDIM + d;
          if (sect == 0)      q_ws[off] = hv;
          else if (sect == 1) k_ws[off] = hv;
          else                v_ws[off] = hv;
        } else {
          fout[(size_t)m * DIMC + n] = v;
        }
      }
}

// ---------------- V transpose: [bh][p][d] -> [bh][d][p] ----------------
__global__ __launch_bounds__(256) void transpose_v(const __bf16* __restrict__ v_ws, __bf16* __restrict__ vt_ws) {
  __shared__ __align__(16) __bf16 t[64][72];   // 144B row stride (16B-aligned rows)
  int bh = blockIdx.y, p0 = blockIdx.x * 64;
  int tid = threadIdx.x;
  const __bf16* src = v_ws + ((size_t)bh * SEQ + p0) * HDIM;
  #pragma unroll
  for (int it = 0; it < 2; ++it) {
    int e = it * 256 + tid;
    int pr = e >> 3, c = (e & 7) * 8;
    bf16x8 val = *reinterpret_cast<const bf16x8*>(src + pr * HDIM + c);
    #pragma unroll
    for (int j = 0; j < 8; ++j) t[c + j][pr] = val[j];
  }
  __syncthreads();
  __bf16* dst = vt_ws + (size_t)bh * HDIM * SEQ + p0;
  #pragma unroll
  for (int it = 0; it < 2; ++it) {
    int e = it * 256 + tid;
    int d = e >> 3, c = (e & 7) * 8;
    bf16x8 val = *reinterpret_cast<const bf16x8*>(&t[d][c]);
    *reinterpret_cast<bf16x8*>(dst + (size_t)d * SEQ + c) = val;
  }
}

// ---------------- flash attention (split-KV x4, atomic partial-O) ----------------
// R8: 512 threads = 8 waves (q-tile 256, 32 rows/wave); split-KV x4 (quarter =
// 1024 kv = 16 tiles); grid 16bh x 16qb x 4 = 1024 = exactly 4 blocks/CU.
// VGPR<=64 via __launch_bounds__(512,8) -> up to 32 waves/CU (2x R7) to fill
// the serial-chain bubbles (R7 post-mortem: stall-bound, pipes at 36/47%).
// Loop body identical to R7: swapped QK^T, T12 in-register P relayout
// (cvt-pack + permlane32/16_swap), no max-shift, deferred denominator.
// Atomics: 4 fp32 contributors per address (order-variation ~1e-7, margin 1e-4).
__global__ __launch_bounds__(512, 8) void attn_kernel(const __bf16* __restrict__ q_ws, const __bf16* __restrict__ k_ws,
                                                      const __bf16* __restrict__ vt_ws,
                                                      float* __restrict__ o_num, float* __restrict__ lsum) {
  __shared__ __align__(16) __bf16 Ks[2][64 * 64];   // [kv][d], swizzled
  __shared__ __align__(16) __bf16 Vts[2][64 * 64];  // [d][kv], swizzled
  const int tid = threadIdx.x;
  const int lane = tid & 63;
  const int r16 = lane & 15, g4 = lane >> 4;
  // XCD-bijective swizzle over 1024 blocks: 128 consecutive wgs (2 heads) per XCD.
  int bid = blockIdx.x;
  int wg = (bid & 7) * 128 + (bid >> 3);
  int bh = wg >> 6, sub = wg & 63;
  int qb = sub >> 2, quarter = sub & 3;
  int b = bh >> 2, h = bh & 3;
  const __bf16* Qp  = q_ws  + (size_t)bh * SEQ * HDIM;
  const __bf16* Kp  = k_ws  + (size_t)bh * SEQ * HDIM;
  const __bf16* Vtp = vt_ws + (size_t)bh * HDIM * SEQ;
  const int q0 = qb * 256 + (tid >> 6) * 32;
  const int kvb = quarter * (SEQ / 4);
  bf16x8 qf[2][2];
  #pragma unroll
  for (int hh = 0; hh < 2; ++hh)
    #pragma unroll
    for (int kk = 0; kk < 2; ++kk)
      qf[hh][kk] = *reinterpret_cast<const bf16x8*>(Qp + (size_t)(q0 + hh * 16 + r16) * HDIM + kk * 32 + g4 * 8);
  f32x4 o_acc[2][4] = {};
  f32x4 rsv[2] = {};                   // per-lane partial denominators (4 chains each)

  // staging: 512 threads x 1 chunk x (16B K + 16B Vt); pre-swizzled source col.
  const int sr = tid >> 3;             // row 0..63
  const int scs = (tid & 7) ^ (sr & 7);
  const __bf16* kSrc = Kp  + (size_t)sr * HDIM + scs * 8;
  const __bf16* vSrc = Vtp + (size_t)sr * SEQ  + scs * 8;

  #define STAGE(buf, kv0) do { \
      gll16(kSrc + (size_t)(kv0) * HDIM, &Ks[buf][tid * 8]); \
      gll16(vSrc + (kv0),                &Vts[buf][tid * 8]); \
    } while (0)

  STAGE(0, kvb);
  __syncthreads();

  int cur = 0;
  for (int t = 0; t < SEQ / 4 / 64; ++t) {
    if (t + 1 < SEQ / 4 / 64) STAGE(cur ^ 1, kvb + (t + 1) * 64);
    // S^T = K Q^T for BOTH halves; kf read once per (ni,kk).
    // D[kv][q]: col=lane&15=q, row=g4*4+r = kv-within-16-block.
    f32x4 s0[4] = {}, s1[4] = {};
    #pragma unroll
    for (int ni = 0; ni < 4; ++ni)
      #pragma unroll
      for (int kk = 0; kk < 2; ++kk) {
        bf16x8 kf = swzread(Ks[cur], ni * 16 + r16, kk * 4 + g4);
        s0[ni] = __builtin_amdgcn_mfma_f32_16x16x32_bf16(kf, qf[0][kk], s0[ni], 0, 0, 0);
        s1[ni] = __builtin_amdgcn_mfma_f32_16x16x32_bf16(kf, qf[1][kk], s1[ni], 0, 0, 0);
      }
    // P = exp2(S); in-register relayout to PV A-frags (T12), no LDS.
    bf16x8 pa[2][2];
    #pragma unroll
    for (int hh = 0; hh < 2; ++hh) {
      unsigned c[4][2];
      #pragma unroll
      for (int ni = 0; ni < 4; ++ni) {
        const f32x4& sv = hh ? s1[ni] : s0[ni];
        float p0 = vexp2(sv[0]), p1 = vexp2(sv[1]);
        float p2 = vexp2(sv[2]), p3 = vexp2(sv[3]);
        rsv[hh] += (f32x4){p0, p1, p2, p3};
        c[ni][0] = pack2(p0, p1);
        c[ni][1] = pack2(p2, p3);
      }
      unsigned tt[2][4];
      #pragma unroll
      for (int kk = 0; kk < 2; ++kk)
        #pragma unroll
        for (int u = 0; u < 2; ++u) {
          uint2v p = __builtin_amdgcn_permlane32_swap(c[2 * kk][u], c[2 * kk + 1][u], false, false);
          uint2v q = __builtin_amdgcn_permlane16_swap(p[0], p[1], false, false);
          tt[kk][u]     = q[0];   // m2=0 -> m = u
          tt[kk][2 + u] = q[1];   // m2=1 -> m = 2+u
        }
      uint4v w0 = {tt[0][0], tt[0][1], tt[0][2], tt[0][3]};
      uint4v w1 = {tt[1][0], tt[1][1], tt[1][2], tt[1][3]};
      pa[hh][0] = __builtin_bit_cast(bf16x8, w0);
      pa[hh][1] = __builtin_bit_cast(bf16x8, w1);
    }
    // O += P V ; vf read once per (kk,di), shared across both halves.
    #pragma unroll
    for (int kk = 0; kk < 2; ++kk)
      #pragma unroll
      for (int di = 0; di < 4; ++di) {
        bf16x8 vf = swzread(Vts[cur], di * 16 + r16, kk * 4 + g4);
        o_acc[0][di] = __builtin_amdgcn_mfma_f32_16x16x32_bf16(pa[0][kk], vf, o_acc[0][di], 0, 0, 0);
        o_acc[1][di] = __builtin_amdgcn_mfma_f32_16x16x32_bf16(pa[1][kk], vf, o_acc[1][di], 0, 0, 0);
      }
    __syncthreads();   // implicit vmcnt(0) drains next-tile loads; frees buf cur
    cur ^= 1;
  }
  // denominators: hsum 4 chains, reduce over g4 groups, one atomic per q-row
  #pragma unroll
  for (int hh = 0; hh < 2; ++hh) {
    float den = (rsv[hh][0] + rsv[hh][1]) + (rsv[hh][2] + rsv[hh][3]);
    den += __shfl_xor(den, 16);
    den += __shfl_xor(den, 32);
    if (lane < 16) atomicAdd(&lsum[(size_t)bh * SEQ + q0 + hh * 16 + r16], den);
  }
  // partial-O accumulate (PV D-layout: col=lane&15=d16, row=g4*4+r=q)
  #pragma unroll
  for (int hh = 0; hh < 2; ++hh)
    #pragma unroll
    for (int di = 0; di < 4; ++di)
      #pragma unroll
      for (int r = 0; r < 4; ++r) {
        int q = q0 + hh * 16 + g4 * 4 + r;
        atomicAdd(&o_num[(size_t)(b * SEQ + q) * DIMC + h * HDIM + di * 16 + r16], o_acc[hh][di][r]);
      }
}

// ---------------- normalize: o_ws = o_num / lsum (fp32 -> bf16) ----------------
__global__ __launch_bounds__(256) void normalize_o(const float* __restrict__ on, const float* __restrict__ lsum,
                                                   __bf16* __restrict__ o_ws) {
  int i = blockIdx.x * 256 + threadIdx.x;
  int flat = i * 4;
  int m = flat >> 8, c = flat & 255;
  int h = c >> 6;
  int b = m >> 12, p = m & 4095;
  float inv = 1.f / lsum[(size_t)(b * NHEADS + h) * SEQ + p];
  float4 n = *reinterpret_cast<const float4*>(on + flat);
  bf16x4 o;
  o[0] = (__bf16)(n.x * inv); o[1] = (__bf16)(n.y * inv);
  o[2] = (__bf16)(n.z * inv); o[3] = (__bf16)(n.w * inv);
  *reinterpret_cast<bf16x4*>(o_ws + flat) = o;
}

// ---------------- launch ----------------

extern "C" void kernel_launch(void* const* d_in, const int* in_sizes, int n_in,
                              void* d_out, int out_size, void* d_ws, size_t ws_size,
                              hipStream_t stream) {
  const float* x  = (const float*)d_in[0];
  const float* Wq = (const float*)d_in[1];
  const float* bq = (const float*)d_in[2];
  const float* Wk = (const float*)d_in[3];
  const float* bk = (const float*)d_in[4];
  const float* Wv = (const float*)d_in[5];
  const float* bv = (const float*)d_in[6];
  const float* Wo = (const float*)d_in[7];
  const float* bo = (const float*)d_in[8];
  float* out = (float*)d_out;

  const size_t NE = (size_t)MTOT * DIMC;  // 4,194,304 elements
  char* w = (char*)d_ws;
  __bf16* q_ws  = (__bf16*)w; w += NE * 2;
  __bf16* k_ws  = (__bf16*)w; w += NE * 2;
  __bf16* vt_ws = (__bf16*)w; w += NE * 2;
  __bf16* wqkvt = (__bf16*)w; w += (size_t)768 * 256 * 2;
  __bf16* wot   = (__bf16*)w; w += (size_t)256 * 256 * 2;
  float*  biasq = (float*)w;  w += 768 * 4;
  float*  lsum  = (float*)w;  w += (size_t)16 * SEQ * 4;      // 256 KB
  float*  o_num = (float*)w;  w += NE * 4;                    // 16 MB, zeroed with lsum
  // aliases: xb/v_ws live only BEFORE the memset of o_num; o_ws only AFTER attn.
  __bf16* xb   = (__bf16*)o_num;                    // first 8 MB of o_num region
  __bf16* v_ws = (__bf16*)((char*)o_num + NE * 2);  // second 8 MB
  __bf16* o_ws = q_ws;                              // q_ws dead after attn
  // total ws used: ~42.7 MB

  cvt_x_kernel<<<MTOT * DIMC / 1024, 256, 0, stream>>>(x, xb);
  prep_w<<<1024, 256, 0, stream>>>(Wq, Wk, Wv, Wo, wqkvt, wot);
  prep_bias<<<3, 256, 0, stream>>>(bq, bk, bv, biasq);
  gemm_bt<0><<<dim3(6, 128), 256, 0, stream>>>(xb, wqkvt, biasq, q_ws, k_ws, v_ws, nullptr);
  transpose_v<<<dim3(64, 16), 256, 0, stream>>>(v_ws, vt_ws);
  hipMemsetAsync(lsum, 0, (size_t)16 * SEQ * 4 + NE * 4, stream);   // lsum + o_num contiguous
  attn_kernel<<<1024, 512, 0, stream>>>(q_ws, k_ws, vt_ws, o_num, lsum);
  normalize_o<<<NE / 1024, 256, 0, stream>>>(o_num, lsum, o_ws);
  gemm_bt<1><<<dim3(2, 128), 256, 0, stream>>>(o_ws, wot, bo, nullptr, nullptr, nullptr, out);
}

// Round 10
// 208.794 us; speedup vs baseline: 2.5255x; 2.5255x over previous
//
#include <hip/hip_runtime.h>
#include <hip/hip_bf16.h>

// MHSA: B=4, P=4096, C=256, H=4, D=64. fp32 in/out, bf16 MFMA internally.
#define DIMC 256
#define NHEADS 4
#define HDIM 64
#define BATCH 4
#define SEQ 4096
#define MTOT (BATCH*SEQ)   // 16384
#define SCALE_LOG2E 0.18033688011112042f  // 0.125 * log2(e); softmax done in exp2 domain

typedef __attribute__((ext_vector_type(8))) __bf16 bf16x8;
typedef __attribute__((ext_vector_type(4))) __bf16 bf16x4;
typedef __attribute__((ext_vector_type(2))) __bf16 bf16x2;
typedef __attribute__((ext_vector_type(4))) float f32x4;
typedef __attribute__((ext_vector_type(2))) unsigned uint2v;
typedef __attribute__((ext_vector_type(4))) unsigned uint4v;

__device__ inline void gll16(const void* g, void* l) {
  // async global->LDS, 16B per lane. LDS dest must be wave-uniform base + lane*16.
  __builtin_amdgcn_global_load_lds((const __attribute__((address_space(1))) unsigned int*)g,
                                   (__attribute__((address_space(3))) unsigned int*)l, 16, 0, 0);
}

// Single v_exp_f32 via the compiler intrinsic. NOTE (R5 post-mortem): raw
// inline-asm v_exp_f32 FAILED — TRANS ops need a wait state before dependent
// VALU consumers and the compiler can't see inside asm. The builtin emits the
// same single instruction WITH correct hazard handling. Args in ~[-2,2].
__device__ inline float vexp2(float x) { return __builtin_amdgcn_exp2f(x); }

// Pack two f32 -> one u32 of 2 bf16 (RNE). Plain casts (NOT inline asm):
// compiler emits cvt_pk/cvt+pack itself and keeps hazard handling (m240).
__device__ inline unsigned pack2(float lo, float hi) {
  bf16x2 p; p[0] = (__bf16)lo; p[1] = (__bf16)hi;
  return __builtin_bit_cast(unsigned, p);
}

// Swizzled read of a 16B chunk from a row-major LDS tile with 64-bf16 (128B) rows.
// Data staged with matching pre-swizzled global source: chunk (r,c) holds global
// column (c ^ (r&7)). Kills the 128B-stride bank conflict (T2; verified R1: 6.5e7 -> 0).
__device__ inline bf16x8 swzread(const __bf16* base, int row, int c16) {
  return *reinterpret_cast<const bf16x8*>(
      reinterpret_cast<const char*>(base) + row * 128 + ((c16 ^ (row & 7)) << 4));
}

// ---------------- prep kernels ----------------

__global__ __launch_bounds__(256) void cvt_x_kernel(const float* __restrict__ x, __bf16* __restrict__ xb) {
  int i = (blockIdx.x * 256 + threadIdx.x) * 4;
  float4 v = *reinterpret_cast<const float4*>(x + i);
  bf16x4 o;
  o[0] = (__bf16)v.x; o[1] = (__bf16)v.y; o[2] = (__bf16)v.z; o[3] = (__bf16)v.w;
  *reinterpret_cast<bf16x4*>(xb + i) = o;
}

// Builds Wqkv^T [768][256] (Wq scaled by 0.125*log2e) and Wo^T [256][256].
__global__ __launch_bounds__(256) void prep_w(const float* __restrict__ Wq, const float* __restrict__ Wk,
                                              const float* __restrict__ Wv, const float* __restrict__ Wo,
                                              __bf16* __restrict__ wqkvt, __bf16* __restrict__ wot) {
  int row = blockIdx.x;        // 0..1023
  int k = threadIdx.x;         // 0..255
  if (row < 768) {
    const float* src; float scale = 1.f; int n = row & 255;
    if (row < 256)      { src = Wq; scale = SCALE_LOG2E; }
    else if (row < 512) { src = Wk; }
    else                { src = Wv; }
    wqkvt[row * 256 + k] = (__bf16)(src[k * 256 + n] * scale);
  } else {
    int n = row - 768;
    wot[n * 256 + k] = (__bf16)(Wo[k * 256 + n]);
  }
}

__global__ __launch_bounds__(256) void prep_bias(const float* __restrict__ bq, const float* __restrict__ bk,
                                                 const float* __restrict__ bv, float* __restrict__ biasq) {
  int i = blockIdx.x * 256 + threadIdx.x;  // 0..767
  biasq[i] = (i < 256) ? bq[i] * SCALE_LOG2E : (i < 512 ? bk[i - 256] : bv[i - 512]);
}

// ---------------- GEMM: C[m][n] = sum_k A[m][k]*Bt[n][k] + bias[n] ----------------
// 128x128 tile, BK=64, 4 waves (2x2 of 64x64), mfma 16x16x32 bf16. T2-swizzled LDS.
// MODE 0: scatter into q/k/v [b][h][p][d] (bf16).  MODE 1: fp32 out [m][256].
template<int MODE>
__global__ __launch_bounds__(256) void gemm_bt(const __bf16* __restrict__ A, const __bf16* __restrict__ Bt,
                                               const float* __restrict__ bias,
                                               __bf16* __restrict__ q_ws, __bf16* __restrict__ k_ws,
                                               __bf16* __restrict__ v_ws, float* __restrict__ fout) {
  __shared__ __align__(16) __bf16 As[128 * 64];
  __shared__ __align__(16) __bf16 Bs[128 * 64];
  const int tid = threadIdx.x;
  const int lane = tid & 63, wave = tid >> 6;
  const int wr = wave >> 1, wc = wave & 1;
  const int r16 = lane & 15, g4 = lane >> 4;
  const int m0 = blockIdx.y * 128, n0 = blockIdx.x * 128;
  f32x4 acc[4][4] = {};
  for (int k0 = 0; k0 < DIMC; k0 += 64) {
    #pragma unroll
    for (int it = 0; it < 4; ++it) {
      int e = it * 256 + tid;           // 16B chunk id
      int r = e >> 3, c = e & 7;
      int cs = c ^ (r & 7);             // pre-swizzled source column (rule #21)
      gll16(A  + (size_t)(m0 + r) * DIMC + k0 + cs * 8, As + e * 8);
      gll16(Bt + (size_t)(n0 + r) * DIMC + k0 + cs * 8, Bs + e * 8);
    }
    __syncthreads();
    #pragma unroll
    for (int kk = 0; kk < 2; ++kk) {
      bf16x8 af[4], bfr[4];
      #pragma unroll
      for (int mi = 0; mi < 4; ++mi)
        af[mi] = swzread(As, wr * 64 + mi * 16 + r16, kk * 4 + g4);
      #pragma unroll
      for (int ni = 0; ni < 4; ++ni)
        bfr[ni] = swzread(Bs, wc * 64 + ni * 16 + r16, kk * 4 + g4);
      #pragma unroll
      for (int mi = 0; mi < 4; ++mi)
        #pragma unroll
        for (int ni = 0; ni < 4; ++ni)
          acc[mi][ni] = __builtin_amdgcn_mfma_f32_16x16x32_bf16(af[mi], bfr[ni], acc[mi][ni], 0, 0, 0);
    }
    __syncthreads();
  }
  // Epilogue. C/D layout: col = lane&15, row = (lane>>4)*4 + reg.
  #pragma unroll
  for (int mi = 0; mi < 4; ++mi)
    #pragma unroll
    for (int ni = 0; ni < 4; ++ni)
      #pragma unroll
      for (int r = 0; r < 4; ++r) {
        int m = m0 + wr * 64 + mi * 16 + g4 * 4 + r;
        int n = n0 + wc * 64 + ni * 16 + r16;
        float v = acc[mi][ni][r] + bias[n];
        if (MODE == 0) {
          int b = m >> 12, p = m & 4095;
          int sect = n >> 8, nc = n & 255;
          int h = nc >> 6, d = nc & 63;
          __bf16 hv = (__bf16)v;
          size_t off = ((size_t)(b * NHEADS + h) * SEQ + p) * HDIM + d;
          if (sect == 0)      q_ws[off] = hv;
          else if (sect == 1) k_ws[off] = hv;
          else                v_ws[off] = hv;
        } else {
          fout[(size_t)m * DIMC + n] = v;
        }
      }
}

// ---------------- V transpose: [bh][p][d] -> [bh][d][p] ----------------
__global__ __launch_bounds__(256) void transpose_v(const __bf16* __restrict__ v_ws, __bf16* __restrict__ vt_ws) {
  __shared__ __align__(16) __bf16 t[64][72];   // 144B row stride (16B-aligned rows)
  int bh = blockIdx.y, p0 = blockIdx.x * 64;
  int tid = threadIdx.x;
  const __bf16* src = v_ws + ((size_t)bh * SEQ + p0) * HDIM;
  #pragma unroll
  for (int it = 0; it < 2; ++it) {
    int e = it * 256 + tid;
    int pr = e >> 3, c = (e & 7) * 8;
    bf16x8 val = *reinterpret_cast<const bf16x8*>(src + pr * HDIM + c);
    #pragma unroll
    for (int j = 0; j < 8; ++j) t[c + j][pr] = val[j];
  }
  __syncthreads();
  __bf16* dst = vt_ws + (size_t)bh * HDIM * SEQ + p0;
  #pragma unroll
  for (int it = 0; it < 2; ++it) {
    int e = it * 256 + tid;
    int d = e >> 3, c = (e & 7) * 8;
    bf16x8 val = *reinterpret_cast<const bf16x8*>(&t[d][c]);
    *reinterpret_cast<bf16x8*>(dst + (size_t)d * SEQ + c) = val;
  }
}

// ---------------- flash attention (split-KV x4, atomic partial-O) ----------------
// R9: EXACT R7 body (256 thr = 4 waves, q-tile 128, 56 VGPR) — R8's (512,8)
// spilled (VGPR budget 64 < need, FETCH 880MB scratch traffic). Occupancy is
// raised the spill-safe way: __launch_bounds__(256,5) (VGPR cap ~102 >= 56)
// + split-KV x4 -> grid 2048 (8/CU queued); LDS 32KB x 5 = 160KB exactly ->
// 5 blocks/CU resident = 20 waves/CU (vs R7's 16). Worst case 4 fit = R7 perf.
// Swapped QK^T, T12 in-register P relayout, no max-shift, deferred denominator.
__global__ __launch_bounds__(256, 5) void attn_kernel(const __bf16* __restrict__ q_ws, const __bf16* __restrict__ k_ws,
                                                      const __bf16* __restrict__ vt_ws,
                                                      float* __restrict__ o_num, float* __restrict__ lsum) {
  __shared__ __align__(16) __bf16 Ks[2][64 * 64];   // [kv][d], swizzled
  __shared__ __align__(16) __bf16 Vts[2][64 * 64];  // [d][kv], swizzled
  const int tid = threadIdx.x;
  const int lane = tid & 63;
  const int r16 = lane & 15, g4 = lane >> 4;
  // XCD-bijective swizzle over 2048 blocks: 256 consecutive wgs (2 heads) per XCD.
  int bid = blockIdx.x;
  int wg = (bid & 7) * 256 + (bid >> 3);
  int bh = wg >> 7, sub = wg & 127;
  int qb = sub >> 2, quarter = sub & 3;
  int b = bh >> 2, h = bh & 3;
  const __bf16* Qp  = q_ws  + (size_t)bh * SEQ * HDIM;
  const __bf16* Kp  = k_ws  + (size_t)bh * SEQ * HDIM;
  const __bf16* Vtp = vt_ws + (size_t)bh * HDIM * SEQ;
  const int q0 = qb * 128 + (tid >> 6) * 32;
  const int kvb = quarter * (SEQ / 4);
  bf16x8 qf[2][2];
  #pragma unroll
  for (int hh = 0; hh < 2; ++hh)
    #pragma unroll
    for (int kk = 0; kk < 2; ++kk)
      qf[hh][kk] = *reinterpret_cast<const bf16x8*>(Qp + (size_t)(q0 + hh * 16 + r16) * HDIM + kk * 32 + g4 * 8);
  f32x4 o_acc[2][4] = {};
  f32x4 rsv[2] = {};                   // per-lane partial denominators (4 chains each)

  // staging: 256 threads x 2 chunks x (16B K + 16B Vt); pre-swizzled source col.
  const int sr = tid >> 3;
  const int scs = (tid & 7) ^ (sr & 7);
  const __bf16* kSrc = Kp  + (size_t)sr * HDIM + scs * 8;
  const __bf16* vSrc = Vtp + (size_t)sr * SEQ  + scs * 8;

  #define STAGE(buf, kv0) do { \
      gll16(kSrc + (size_t)(kv0) * HDIM,        &Ks[buf][tid * 8]); \
      gll16(kSrc + (size_t)((kv0) + 32) * HDIM, &Ks[buf][(tid + 256) * 8]); \
      gll16(vSrc + (kv0),                       &Vts[buf][tid * 8]); \
      gll16(vSrc + 32 * SEQ + (kv0),            &Vts[buf][(tid + 256) * 8]); \
    } while (0)

  STAGE(0, kvb);
  __syncthreads();

  int cur = 0;
  for (int t = 0; t < SEQ / 4 / 64; ++t) {
    if (t + 1 < SEQ / 4 / 64) STAGE(cur ^ 1, kvb + (t + 1) * 64);
    // S^T = K Q^T for BOTH halves; kf read once per (ni,kk).
    // D[kv][q]: col=lane&15=q, row=g4*4+r = kv-within-16-block.
    f32x4 s0[4] = {}, s1[4] = {};
    #pragma unroll
    for (int ni = 0; ni < 4; ++ni)
      #pragma unroll
      for (int kk = 0; kk < 2; ++kk) {
        bf16x8 kf = swzread(Ks[cur], ni * 16 + r16, kk * 4 + g4);
        s0[ni] = __builtin_amdgcn_mfma_f32_16x16x32_bf16(kf, qf[0][kk], s0[ni], 0, 0, 0);
        s1[ni] = __builtin_amdgcn_mfma_f32_16x16x32_bf16(kf, qf[1][kk], s1[ni], 0, 0, 0);
      }
    // P = exp2(S); in-register relayout to PV A-frags (T12), no LDS.
    bf16x8 pa[2][2];
    #pragma unroll
    for (int hh = 0; hh < 2; ++hh) {
      unsigned c[4][2];
      #pragma unroll
      for (int ni = 0; ni < 4; ++ni) {
        const f32x4& sv = hh ? s1[ni] : s0[ni];
        float p0 = vexp2(sv[0]), p1 = vexp2(sv[1]);
        float p2 = vexp2(sv[2]), p3 = vexp2(sv[3]);
        rsv[hh] += (f32x4){p0, p1, p2, p3};
        c[ni][0] = pack2(p0, p1);
        c[ni][1] = pack2(p2, p3);
      }
      unsigned tt[2][4];
      #pragma unroll
      for (int kk = 0; kk < 2; ++kk)
        #pragma unroll
        for (int u = 0; u < 2; ++u) {
          uint2v p = __builtin_amdgcn_permlane32_swap(c[2 * kk][u], c[2 * kk + 1][u], false, false);
          uint2v q = __builtin_amdgcn_permlane16_swap(p[0], p[1], false, false);
          tt[kk][u]     = q[0];   // m2=0 -> m = u
          tt[kk][2 + u] = q[1];   // m2=1 -> m = 2+u
        }
      uint4v w0 = {tt[0][0], tt[0][1], tt[0][2], tt[0][3]};
      uint4v w1 = {tt[1][0], tt[1][1], tt[1][2], tt[1][3]};
      pa[hh][0] = __builtin_bit_cast(bf16x8, w0);
      pa[hh][1] = __builtin_bit_cast(bf16x8, w1);
    }
    // O += P V ; vf read once per (kk,di), shared across both halves.
    #pragma unroll
    for (int kk = 0; kk < 2; ++kk)
      #pragma unroll
      for (int di = 0; di < 4; ++di) {
        bf16x8 vf = swzread(Vts[cur], di * 16 + r16, kk * 4 + g4);
        o_acc[0][di] = __builtin_amdgcn_mfma_f32_16x16x32_bf16(pa[0][kk], vf, o_acc[0][di], 0, 0, 0);
        o_acc[1][di] = __builtin_amdgcn_mfma_f32_16x16x32_bf16(pa[1][kk], vf, o_acc[1][di], 0, 0, 0);
      }
    __syncthreads();   // implicit vmcnt(0) drains next-tile loads; frees buf cur
    cur ^= 1;
  }
  // denominators: hsum 4 chains, reduce over g4 groups, one atomic per q-row
  #pragma unroll
  for (int hh = 0; hh < 2; ++hh) {
    float den = (rsv[hh][0] + rsv[hh][1]) + (rsv[hh][2] + rsv[hh][3]);
    den += __shfl_xor(den, 16);
    den += __shfl_xor(den, 32);
    if (lane < 16) atomicAdd(&lsum[(size_t)bh * SEQ + q0 + hh * 16 + r16], den);
  }
  // partial-O accumulate (PV D-layout: col=lane&15=d16, row=g4*4+r=q)
  #pragma unroll
  for (int hh = 0; hh < 2; ++hh)
    #pragma unroll
    for (int di = 0; di < 4; ++di)
      #pragma unroll
      for (int r = 0; r < 4; ++r) {
        int q = q0 + hh * 16 + g4 * 4 + r;
        atomicAdd(&o_num[(size_t)(b * SEQ + q) * DIMC + h * HDIM + di * 16 + r16], o_acc[hh][di][r]);
      }
}

// ---------------- normalize: o_ws = o_num / lsum (fp32 -> bf16) ----------------
__global__ __launch_bounds__(256) void normalize_o(const float* __restrict__ on, const float* __restrict__ lsum,
                                                   __bf16* __restrict__ o_ws) {
  int i = blockIdx.x * 256 + threadIdx.x;
  int flat = i * 4;
  int m = flat >> 8, c = flat & 255;
  int h = c >> 6;
  int b = m >> 12, p = m & 4095;
  float inv = 1.f / lsum[(size_t)(b * NHEADS + h) * SEQ + p];
  float4 n = *reinterpret_cast<const float4*>(on + flat);
  bf16x4 o;
  o[0] = (__bf16)(n.x * inv); o[1] = (__bf16)(n.y * inv);
  o[2] = (__bf16)(n.z * inv); o[3] = (__bf16)(n.w * inv);
  *reinterpret_cast<bf16x4*>(o_ws + flat) = o;
}

// ---------------- launch ----------------

extern "C" void kernel_launch(void* const* d_in, const int* in_sizes, int n_in,
                              void* d_out, int out_size, void* d_ws, size_t ws_size,
                              hipStream_t stream) {
  const float* x  = (const float*)d_in[0];
  const float* Wq = (const float*)d_in[1];
  const float* bq = (const float*)d_in[2];
  const float* Wk = (const float*)d_in[3];
  const float* bk = (const float*)d_in[4];
  const float* Wv = (const float*)d_in[5];
  const float* bv = (const float*)d_in[6];
  const float* Wo = (const float*)d_in[7];
  const float* bo = (const float*)d_in[8];
  float* out = (float*)d_out;

  const size_t NE = (size_t)MTOT * DIMC;  // 4,194,304 elements
  char* w = (char*)d_ws;
  __bf16* q_ws  = (__bf16*)w; w += NE * 2;
  __bf16* k_ws  = (__bf16*)w; w += NE * 2;
  __bf16* vt_ws = (__bf16*)w; w += NE * 2;
  __bf16* wqkvt = (__bf16*)w; w += (size_t)768 * 256 * 2;
  __bf16* wot   = (__bf16*)w; w += (size_t)256 * 256 * 2;
  float*  biasq = (float*)w;  w += 768 * 4;
  float*  lsum  = (float*)w;  w += (size_t)16 * SEQ * 4;      // 256 KB
  float*  o_num = (float*)w;  w += NE * 4;                    // 16 MB, zeroed with lsum
  // aliases: xb/v_ws live only BEFORE the memset of o_num; o_ws only AFTER attn.
  __bf16* xb   = (__bf16*)o_num;                    // first 8 MB of o_num region
  __bf16* v_ws = (__bf16*)((char*)o_num + NE * 2);  // second 8 MB
  __bf16* o_ws = q_ws;                              // q_ws dead after attn
  // total ws used: ~42.7 MB

  cvt_x_kernel<<<MTOT * DIMC / 1024, 256, 0, stream>>>(x, xb);
  prep_w<<<1024, 256, 0, stream>>>(Wq, Wk, Wv, Wo, wqkvt, wot);
  prep_bias<<<3, 256, 0, stream>>>(bq, bk, bv, biasq);
  gemm_bt<0><<<dim3(6, 128), 256, 0, stream>>>(xb, wqkvt, biasq, q_ws, k_ws, v_ws, nullptr);
  transpose_v<<<dim3(64, 16), 256, 0, stream>>>(v_ws, vt_ws);
  hipMemsetAsync(lsum, 0, (size_t)16 * SEQ * 4 + NE * 4, stream);   // lsum + o_num contiguous
  attn_kernel<<<2048, 256, 0, stream>>>(q_ws, k_ws, vt_ws, o_num, lsum);
  normalize_o<<<NE / 1024, 256, 0, stream>>>(o_num, lsum, o_ws);
  gemm_bt<1><<<dim3(2, 128), 256, 0, stream>>>(o_ws, wot, bo, nullptr, nullptr, nullptr, out);
}

// Round 11
// 138.340 us; speedup vs baseline: 3.8117x; 1.5093x over previous
//
#include <hip/hip_runtime.h>
#include <hip/hip_bf16.h>

// MHSA: B=4, P=4096, C=256, H=4, D=64. fp32 in/out, bf16 MFMA internally.
#define DIMC 256
#define NHEADS 4
#define HDIM 64
#define BATCH 4
#define SEQ 4096
#define MTOT (BATCH*SEQ)   // 16384
#define SCALE_LOG2E 0.18033688011112042f  // 0.125 * log2(e); softmax done in exp2 domain

typedef __attribute__((ext_vector_type(8))) __bf16 bf16x8;
typedef __attribute__((ext_vector_type(4))) __bf16 bf16x4;
typedef __attribute__((ext_vector_type(2))) __bf16 bf16x2;
typedef __attribute__((ext_vector_type(4))) float f32x4;
typedef __attribute__((ext_vector_type(2))) unsigned uint2v;
typedef __attribute__((ext_vector_type(4))) unsigned uint4v;

__device__ inline void gll16(const void* g, void* l) {
  // async global->LDS, 16B per lane. LDS dest must be wave-uniform base + lane*16.
  __builtin_amdgcn_global_load_lds((const __attribute__((address_space(1))) unsigned int*)g,
                                   (__attribute__((address_space(3))) unsigned int*)l, 16, 0, 0);
}

// Single v_exp_f32 via the compiler intrinsic. NOTE (R5 post-mortem): raw
// inline-asm v_exp_f32 FAILED — TRANS ops need a wait state before dependent
// VALU consumers and the compiler can't see inside asm. The builtin emits the
// same single instruction WITH correct hazard handling. Args in ~[-2,2].
__device__ inline float vexp2(float x) { return __builtin_amdgcn_exp2f(x); }

// Pack two f32 -> one u32 of 2 bf16 (RNE). Plain casts (NOT inline asm).
__device__ inline unsigned pack2(float lo, float hi) {
  bf16x2 p; p[0] = (__bf16)lo; p[1] = (__bf16)hi;
  return __builtin_bit_cast(unsigned, p);
}

// Swizzled read of a 16B chunk from a row-major LDS tile with 64-bf16 (128B) rows.
// Data staged with matching pre-swizzled global source: chunk (r,c) holds global
// column (c ^ (r&7)). Kills the 128B-stride bank conflict (T2; verified R1: 6.5e7 -> 0).
__device__ inline bf16x8 swzread(const __bf16* base, int row, int c16) {
  return *reinterpret_cast<const bf16x8*>(
      reinterpret_cast<const char*>(base) + row * 128 + ((c16 ^ (row & 7)) << 4));
}

// ---------------- prep kernels ----------------

__global__ __launch_bounds__(256) void cvt_x_kernel(const float* __restrict__ x, __bf16* __restrict__ xb) {
  int i = (blockIdx.x * 256 + threadIdx.x) * 4;
  float4 v = *reinterpret_cast<const float4*>(x + i);
  bf16x4 o;
  o[0] = (__bf16)v.x; o[1] = (__bf16)v.y; o[2] = (__bf16)v.z; o[3] = (__bf16)v.w;
  *reinterpret_cast<bf16x4*>(xb + i) = o;
}

// Builds Wqkv^T [768][256] (Wq scaled by 0.125*log2e), Wo^T [256][256], and
// (rows 1024..1026) the scaled/merged qkv bias — prep_bias folded in (R10).
__global__ __launch_bounds__(256) void prep_w(const float* __restrict__ Wq, const float* __restrict__ Wk,
                                              const float* __restrict__ Wv, const float* __restrict__ Wo,
                                              const float* __restrict__ bq, const float* __restrict__ bk,
                                              const float* __restrict__ bv,
                                              __bf16* __restrict__ wqkvt, __bf16* __restrict__ wot,
                                              float* __restrict__ biasq) {
  int row = blockIdx.x;        // 0..1026
  int k = threadIdx.x;         // 0..255
  if (row < 768) {
    const float* src; float scale = 1.f; int n = row & 255;
    if (row < 256)      { src = Wq; scale = SCALE_LOG2E; }
    else if (row < 512) { src = Wk; }
    else                { src = Wv; }
    wqkvt[row * 256 + k] = (__bf16)(src[k * 256 + n] * scale);
  } else if (row < 1024) {
    int n = row - 768;
    wot[n * 256 + k] = (__bf16)(Wo[k * 256 + n]);
  } else {
    int i = (row - 1024) * 256 + k;   // 0..767
    biasq[i] = (i < 256) ? bq[i] * SCALE_LOG2E : (i < 512 ? bk[i - 256] : bv[i - 512]);
  }
}

// ---------------- GEMM: C[m][n] = sum_k A[m][k]*Bt[n][k] + bias[n] ----------------
// 128x128 tile, BK=64, 4 waves (2x2 of 64x64), mfma 16x16x32 bf16. T2-swizzled LDS.
// MODE 0: scatter q/k into [bh][p][d] and V DIRECTLY TRANSPOSED into vt [bh][d][p]
//         (R10: replaces the separate transpose_v kernel).  MODE 1: fp32 out.
template<int MODE>
__global__ __launch_bounds__(256) void gemm_bt(const __bf16* __restrict__ A, const __bf16* __restrict__ Bt,
                                               const float* __restrict__ bias,
                                               __bf16* __restrict__ q_ws, __bf16* __restrict__ k_ws,
                                               __bf16* __restrict__ vt_ws, float* __restrict__ fout) {
  __shared__ __align__(16) __bf16 As[128 * 64];
  __shared__ __align__(16) __bf16 Bs[128 * 64];
  const int tid = threadIdx.x;
  const int lane = tid & 63, wave = tid >> 6;
  const int wr = wave >> 1, wc = wave & 1;
  const int r16 = lane & 15, g4 = lane >> 4;
  const int m0 = blockIdx.y * 128, n0 = blockIdx.x * 128;
  f32x4 acc[4][4] = {};
  for (int k0 = 0; k0 < DIMC; k0 += 64) {
    #pragma unroll
    for (int it = 0; it < 4; ++it) {
      int e = it * 256 + tid;           // 16B chunk id
      int r = e >> 3, c = e & 7;
      int cs = c ^ (r & 7);             // pre-swizzled source column (rule #21)
      gll16(A  + (size_t)(m0 + r) * DIMC + k0 + cs * 8, As + e * 8);
      gll16(Bt + (size_t)(n0 + r) * DIMC + k0 + cs * 8, Bs + e * 8);
    }
    __syncthreads();
    #pragma unroll
    for (int kk = 0; kk < 2; ++kk) {
      bf16x8 af[4], bfr[4];
      #pragma unroll
      for (int mi = 0; mi < 4; ++mi)
        af[mi] = swzread(As, wr * 64 + mi * 16 + r16, kk * 4 + g4);
      #pragma unroll
      for (int ni = 0; ni < 4; ++ni)
        bfr[ni] = swzread(Bs, wc * 64 + ni * 16 + r16, kk * 4 + g4);
      #pragma unroll
      for (int mi = 0; mi < 4; ++mi)
        #pragma unroll
        for (int ni = 0; ni < 4; ++ni)
          acc[mi][ni] = __builtin_amdgcn_mfma_f32_16x16x32_bf16(af[mi], bfr[ni], acc[mi][ni], 0, 0, 0);
    }
    __syncthreads();
  }
  // Epilogue. C/D layout: col = lane&15, row = (lane>>4)*4 + reg.
  #pragma unroll
  for (int mi = 0; mi < 4; ++mi)
    #pragma unroll
    for (int ni = 0; ni < 4; ++ni)
      #pragma unroll
      for (int r = 0; r < 4; ++r) {
        int m = m0 + wr * 64 + mi * 16 + g4 * 4 + r;
        int n = n0 + wc * 64 + ni * 16 + r16;
        float v = acc[mi][ni][r] + bias[n];
        if (MODE == 0) {
          int b = m >> 12, p = m & 4095;
          int sect = n >> 8, nc = n & 255;
          int h = nc >> 6, d = nc & 63;
          __bf16 hv = (__bf16)v;
          size_t bhb = (size_t)(b * NHEADS + h);
          if (sect == 0)      q_ws[(bhb * SEQ + p) * HDIM + d] = hv;
          else if (sect == 1) k_ws[(bhb * SEQ + p) * HDIM + d] = hv;
          else                vt_ws[(bhb * HDIM + d) * SEQ + p] = hv;  // direct V^T
        } else {
          fout[(size_t)m * DIMC + n] = v;
        }
      }
}

// ---------------- flash attention (split-KV x2, atomic partial-O) ----------------
// R10 = EXACT R7 config (the 93 µs proven point: 256 thr = 4 waves, q-tile 128,
// split-KV x2, 56 VGPR, grid 1024 = 4 blocks/CU) + T5 s_setprio around the MFMA
// clusters (m191: helps when independent blocks sit at different phases).
// R8 lesson: (512,8) halves the VGPR budget -> spill catastrophe. R9 lesson:
// split x4 doubles cross-XCD atomic ping-pong + Q refetch -> HBM-bound.
// Swapped QK^T, T12 in-register P relayout, no max-shift, deferred denominator.
__global__ __launch_bounds__(256, 4) void attn_kernel(const __bf16* __restrict__ q_ws, const __bf16* __restrict__ k_ws,
                                                      const __bf16* __restrict__ vt_ws,
                                                      float* __restrict__ o_num, float* __restrict__ lsum) {
  __shared__ __align__(16) __bf16 Ks[2][64 * 64];   // [kv][d], swizzled
  __shared__ __align__(16) __bf16 Vts[2][64 * 64];  // [d][kv], swizzled
  const int tid = threadIdx.x;
  const int lane = tid & 63;
  const int r16 = lane & 15, g4 = lane >> 4;
  // XCD-bijective swizzle over 1024 blocks: 128 consecutive wgs (2 heads) per XCD.
  int bid = blockIdx.x;
  int wg = (bid & 7) * 128 + (bid >> 3);
  int bh = wg >> 6, rrw = wg & 63;
  int qb = rrw >> 1, half = rrw & 1;
  int b = bh >> 2, h = bh & 3;
  const __bf16* Qp  = q_ws  + (size_t)bh * SEQ * HDIM;
  const __bf16* Kp  = k_ws  + (size_t)bh * SEQ * HDIM;
  const __bf16* Vtp = vt_ws + (size_t)bh * HDIM * SEQ;
  const int q0 = qb * 128 + (tid >> 6) * 32;
  const int kvb = half * (SEQ / 2);
  bf16x8 qf[2][2];
  #pragma unroll
  for (int hh = 0; hh < 2; ++hh)
    #pragma unroll
    for (int kk = 0; kk < 2; ++kk)
      qf[hh][kk] = *reinterpret_cast<const bf16x8*>(Qp + (size_t)(q0 + hh * 16 + r16) * HDIM + kk * 32 + g4 * 8);
  f32x4 o_acc[2][4] = {};
  f32x4 rsv[2] = {};                   // per-lane partial denominators (4 chains each)

  // staging: 256 threads x 2 chunks x (16B K + 16B Vt); pre-swizzled source col.
  const int sr = tid >> 3;
  const int scs = (tid & 7) ^ (sr & 7);
  const __bf16* kSrc = Kp  + (size_t)sr * HDIM + scs * 8;
  const __bf16* vSrc = Vtp + (size_t)sr * SEQ  + scs * 8;

  #define STAGE(buf, kv0) do { \
      gll16(kSrc + (size_t)(kv0) * HDIM,        &Ks[buf][tid * 8]); \
      gll16(kSrc + (size_t)((kv0) + 32) * HDIM, &Ks[buf][(tid + 256) * 8]); \
      gll16(vSrc + (kv0),                       &Vts[buf][tid * 8]); \
      gll16(vSrc + 32 * SEQ + (kv0),            &Vts[buf][(tid + 256) * 8]); \
    } while (0)

  STAGE(0, kvb);
  __syncthreads();

  int cur = 0;
  for (int t = 0; t < SEQ / 128; ++t) {
    if (t + 1 < SEQ / 128) STAGE(cur ^ 1, kvb + (t + 1) * 64);
    // S^T = K Q^T for BOTH halves; kf read once per (ni,kk).
    // D[kv][q]: col=lane&15=q, row=g4*4+r = kv-within-16-block.
    f32x4 s0[4] = {}, s1[4] = {};
    __builtin_amdgcn_s_setprio(1);
    #pragma unroll
    for (int ni = 0; ni < 4; ++ni)
      #pragma unroll
      for (int kk = 0; kk < 2; ++kk) {
        bf16x8 kf = swzread(Ks[cur], ni * 16 + r16, kk * 4 + g4);
        s0[ni] = __builtin_amdgcn_mfma_f32_16x16x32_bf16(kf, qf[0][kk], s0[ni], 0, 0, 0);
        s1[ni] = __builtin_amdgcn_mfma_f32_16x16x32_bf16(kf, qf[1][kk], s1[ni], 0, 0, 0);
      }
    __builtin_amdgcn_s_setprio(0);
    // P = exp2(S); in-register relayout to PV A-frags (T12), no LDS.
    bf16x8 pa[2][2];
    #pragma unroll
    for (int hh = 0; hh < 2; ++hh) {
      unsigned c[4][2];
      #pragma unroll
      for (int ni = 0; ni < 4; ++ni) {
        const f32x4& sv = hh ? s1[ni] : s0[ni];
        float p0 = vexp2(sv[0]), p1 = vexp2(sv[1]);
        float p2 = vexp2(sv[2]), p3 = vexp2(sv[3]);
        rsv[hh] += (f32x4){p0, p1, p2, p3};
        c[ni][0] = pack2(p0, p1);
        c[ni][1] = pack2(p2, p3);
      }
      unsigned tt[2][4];
      #pragma unroll
      for (int kk = 0; kk < 2; ++kk)
        #pragma unroll
        for (int u = 0; u < 2; ++u) {
          uint2v p = __builtin_amdgcn_permlane32_swap(c[2 * kk][u], c[2 * kk + 1][u], false, false);
          uint2v q = __builtin_amdgcn_permlane16_swap(p[0], p[1], false, false);
          tt[kk][u]     = q[0];   // m2=0 -> m = u
          tt[kk][2 + u] = q[1];   // m2=1 -> m = 2+u
        }
      uint4v w0 = {tt[0][0], tt[0][1], tt[0][2], tt[0][3]};
      uint4v w1 = {tt[1][0], tt[1][1], tt[1][2], tt[1][3]};
      pa[hh][0] = __builtin_bit_cast(bf16x8, w0);
      pa[hh][1] = __builtin_bit_cast(bf16x8, w1);
    }
    // O += P V ; vf read once per (kk,di), shared across both halves.
    __builtin_amdgcn_s_setprio(1);
    #pragma unroll
    for (int kk = 0; kk < 2; ++kk)
      #pragma unroll
      for (int di = 0; di < 4; ++di) {
        bf16x8 vf = swzread(Vts[cur], di * 16 + r16, kk * 4 + g4);
        o_acc[0][di] = __builtin_amdgcn_mfma_f32_16x16x32_bf16(pa[0][kk], vf, o_acc[0][di], 0, 0, 0);
        o_acc[1][di] = __builtin_amdgcn_mfma_f32_16x16x32_bf16(pa[1][kk], vf, o_acc[1][di], 0, 0, 0);
      }
    __builtin_amdgcn_s_setprio(0);
    __syncthreads();   // implicit vmcnt(0) drains next-tile loads; frees buf cur
    cur ^= 1;
  }
  // denominators: hsum 4 chains, reduce over g4 groups, one atomic per q-row
  #pragma unroll
  for (int hh = 0; hh < 2; ++hh) {
    float den = (rsv[hh][0] + rsv[hh][1]) + (rsv[hh][2] + rsv[hh][3]);
    den += __shfl_xor(den, 16);
    den += __shfl_xor(den, 32);
    if (lane < 16) atomicAdd(&lsum[(size_t)bh * SEQ + q0 + hh * 16 + r16], den);
  }
  // partial-O accumulate (PV D-layout: col=lane&15=d16, row=g4*4+r=q)
  #pragma unroll
  for (int hh = 0; hh < 2; ++hh)
    #pragma unroll
    for (int di = 0; di < 4; ++di)
      #pragma unroll
      for (int r = 0; r < 4; ++r) {
        int q = q0 + hh * 16 + g4 * 4 + r;
        atomicAdd(&o_num[(size_t)(b * SEQ + q) * DIMC + h * HDIM + di * 16 + r16], o_acc[hh][di][r]);
      }
}

// ---------------- normalize: o_ws = o_num / lsum (fp32 -> bf16) ----------------
__global__ __launch_bounds__(256) void normalize_o(const float* __restrict__ on, const float* __restrict__ lsum,
                                                   __bf16* __restrict__ o_ws) {
  int i = blockIdx.x * 256 + threadIdx.x;
  int flat = i * 4;
  int m = flat >> 8, c = flat & 255;
  int h = c >> 6;
  int b = m >> 12, p = m & 4095;
  float inv = 1.f / lsum[(size_t)(b * NHEADS + h) * SEQ + p];
  float4 n = *reinterpret_cast<const float4*>(on + flat);
  bf16x4 o;
  o[0] = (__bf16)(n.x * inv); o[1] = (__bf16)(n.y * inv);
  o[2] = (__bf16)(n.z * inv); o[3] = (__bf16)(n.w * inv);
  *reinterpret_cast<bf16x4*>(o_ws + flat) = o;
}

// ---------------- launch ----------------

extern "C" void kernel_launch(void* const* d_in, const int* in_sizes, int n_in,
                              void* d_out, int out_size, void* d_ws, size_t ws_size,
                              hipStream_t stream) {
  const float* x  = (const float*)d_in[0];
  const float* Wq = (const float*)d_in[1];
  const float* bq = (const float*)d_in[2];
  const float* Wk = (const float*)d_in[3];
  const float* bk = (const float*)d_in[4];
  const float* Wv = (const float*)d_in[5];
  const float* bv = (const float*)d_in[6];
  const float* Wo = (const float*)d_in[7];
  const float* bo = (const float*)d_in[8];
  float* out = (float*)d_out;

  const size_t NE = (size_t)MTOT * DIMC;  // 4,194,304 elements
  char* w = (char*)d_ws;
  __bf16* q_ws  = (__bf16*)w; w += NE * 2;
  __bf16* k_ws  = (__bf16*)w; w += NE * 2;
  __bf16* vt_ws = (__bf16*)w; w += NE * 2;
  __bf16* wqkvt = (__bf16*)w; w += (size_t)768 * 256 * 2;
  __bf16* wot   = (__bf16*)w; w += (size_t)256 * 256 * 2;
  float*  biasq = (float*)w;  w += 768 * 4;
  float*  lsum  = (float*)w;  w += (size_t)16 * SEQ * 4;      // 256 KB
  float*  o_num = (float*)w;  w += NE * 4;                    // 16 MB, zeroed with lsum
  // aliases: xb lives only BEFORE the memset of o_num; o_ws only AFTER attn.
  __bf16* xb   = (__bf16*)o_num;                    // first 8 MB of o_num region
  __bf16* o_ws = q_ws;                              // q_ws dead after attn
  // total ws used: ~40.8 MB

  cvt_x_kernel<<<MTOT * DIMC / 1024, 256, 0, stream>>>(x, xb);
  prep_w<<<1027, 256, 0, stream>>>(Wq, Wk, Wv, Wo, bq, bk, bv, wqkvt, wot, biasq);
  gemm_bt<0><<<dim3(6, 128), 256, 0, stream>>>(xb, wqkvt, biasq, q_ws, k_ws, vt_ws, nullptr);
  hipMemsetAsync(lsum, 0, (size_t)16 * SEQ * 4 + NE * 4, stream);   // lsum + o_num contiguous
  attn_kernel<<<1024, 256, 0, stream>>>(q_ws, k_ws, vt_ws, o_num, lsum);
  normalize_o<<<NE / 1024, 256, 0, stream>>>(o_num, lsum, o_ws);
  gemm_bt<1><<<dim3(2, 128), 256, 0, stream>>>(o_ws, wot, bo, nullptr, nullptr, nullptr, out);
}